// Round 4
// baseline (178.099 us; speedup 1.0000x reference)
//
#include <hip/hip_runtime.h>
#include <math.h>

#define BATCH 64
#define LSEQ 4096
#define CH 128
#define NCHUNK 32
#define CHROWS (LSEQ / NCHUNK)   // 128
#define TROWS (CHROWS / 8)       // 16 rows per thread
#define NRECENT 1024             // chunks 24..31

typedef float f4v __attribute__((ext_vector_type(4)));

// ws layout: partials[(b*NCHUNK+chk)*5 + s][c] (5.24 MB), then BATCH u32 tickets
#define WS_PART_ELEMS ((size_t)BATCH * NCHUNK * 5 * CH)

__global__ __launch_bounds__(256) void k_fused(
    const float* __restrict__ x,
    const float* __restrict__ W1, const float* __restrict__ b1,
    const float* __restrict__ W2, const float* __restrict__ b2,
    const float* __restrict__ W3, const float* __restrict__ b3,
    float* __restrict__ ws, unsigned* __restrict__ cnt,
    float* __restrict__ out) {
  const int tid = threadIdx.x;
  const int c4 = tid & 31;        // float4 group -> channels 4*c4..4*c4+3
  const int ty = tid >> 5;        // 0..7
  const int chk = blockIdx.x;
  const int b = blockIdx.y;
  const int ts = chk * CHROWS + ty * TROWS;

  // ---- LDS (hand-unioned): A = red(10240B)/part(7168B), B = MLP buffers ----
  __shared__ __align__(16) float smemA[2560];
  __shared__ __align__(16) float smemB[1696];
  __shared__ unsigned ticket;

  // ================= streaming phase =================
  {
    const f4v* px =
        reinterpret_cast<const f4v*>(x + ((size_t)b * LSEQ + ts) * CH) + c4;
    const int rowstep = CH / 4;

    float sx[4] = {0, 0, 0, 0}, sx2[4] = {0, 0, 0, 0}, sx3[4] = {0, 0, 0, 0};
    float sd2[4] = {0, 0, 0, 0};
    float pv[4], first[4], sd[4];

    f4v v0 = __builtin_nontemporal_load(px);
#pragma unroll
    for (int k = 0; k < 4; k++) {
      pv[k] = first[k] = v0[k];
      float f = pv[k], ff = f * f;
      sx[k] += f; sx2[k] += ff; sx3[k] = fmaf(ff, f, sx3[k]);
    }
#pragma unroll 5
    for (int i = 1; i < TROWS; i++) {
      f4v u = __builtin_nontemporal_load(px + i * rowstep);
#pragma unroll
      for (int k = 0; k < 4; k++) {
        float f = u[k], ff = f * f;
        sx[k] += f; sx2[k] += ff; sx3[k] = fmaf(ff, f, sx3[k]);
        float d = f - pv[k];
        sd2[k] = fmaf(d, d, sd2[k]);
        pv[k] = f;
      }
    }
    if (ts + TROWS < LSEQ) {  // boundary diff into next range, telescoped sd
      f4v u = __builtin_nontemporal_load(px + TROWS * rowstep);
#pragma unroll
      for (int k = 0; k < 4; k++) {
        float d = u[k] - pv[k];
        sd2[k] = fmaf(d, d, sd2[k]);
        sd[k] = u[k] - first[k];
      }
    } else {
#pragma unroll
      for (int k = 0; k < 4; k++) sd[k] = pv[k] - first[k];
    }

    float vals[20];
#pragma unroll
    for (int k = 0; k < 4; k++) {
      vals[0 + k] = sx[k];
      vals[4 + k] = sx2[k];
      vals[8 + k] = sx3[k];
      vals[12 + k] = sd[k];
      vals[16 + k] = sd2[k];
    }
#pragma unroll
    for (int j = 0; j < 20; j++) vals[j] += __shfl_xor(vals[j], 32);

    float4* red = reinterpret_cast<float4*>(smemA);  // [s][w][c] = [(s*4+w)*32+c]
    const int w = tid >> 6;
    if ((tid & 63) < 32) {
#pragma unroll
      for (int s = 0; s < 5; s++)
        red[(s * 4 + w) * 32 + c4] = make_float4(vals[s * 4 + 0], vals[s * 4 + 1],
                                                 vals[s * 4 + 2], vals[s * 4 + 3]);
    }
    __syncthreads();
    if (tid < 160) {
      const int s = tid >> 5, c = tid & 31;
      float4 r = red[(s * 4 + 0) * 32 + c];
      float4 r1 = red[(s * 4 + 1) * 32 + c];
      float4 r2 = red[(s * 4 + 2) * 32 + c];
      float4 r3 = red[(s * 4 + 3) * 32 + c];
      r.x += r1.x + r2.x + r3.x;
      r.y += r1.y + r2.y + r3.y;
      r.z += r1.z + r2.z + r3.z;
      r.w += r1.w + r2.w + r3.w;
      float* wsb = ws + ((size_t)(b * NCHUNK + chk) * 5 + s) * CH;
      reinterpret_cast<float4*>(wsb)[c] = r;
    }
  }
  __syncthreads();

  // ================= ticket =================
  if (tid == 0) {
    __threadfence();                       // release: push partials out of this XCD's L2
    ticket = atomicAdd(&cnt[b], 1u);
  }
  __syncthreads();
  if (ticket != NCHUNK - 1) return;        // uniform per block
  __threadfence();                         // acquire

  // ================= finalize batch b (last block only) =================
  const int f = tid & 127;
  const int h = tid >> 7;  // 0..1

  float* part = smemA;              // [s(7)][h(2)][128]
  float* stats = smemB;             // 768
  float* h1p = smemB + 768;         // [2][128]
  float* h1 = smemB + 1024;         // 128
  float* h2p = smemB + 1152;        // [8][32]
  float* h2 = smemB + 1408;         // 32
  float* l3p = smemB + 1440;        // [2][128]

  // ---- chunk reduce: half h sums chunks [16h, 16h+16) ----
  {
    float t0 = 0, t1 = 0, t2 = 0, t3 = 0, t4 = 0, r0 = 0, r1 = 0;
    const float* base = ws + (size_t)(b * NCHUNK) * 5 * CH + f;
#pragma unroll 4
    for (int c = 16 * h; c < 16 * h + 16; c++) {
      const float* p = base + (size_t)c * 5 * CH;
      float a0 = p[0 * CH], a1 = p[1 * CH], a2 = p[2 * CH];
      float a3 = p[3 * CH], a4 = p[4 * CH];
      t0 += a0; t1 += a1; t2 += a2; t3 += a3; t4 += a4;
      if (c >= 24) { r0 += a0; r1 += a1; }   // recent window, uniform branch
    }
    part[(0 * 2 + h) * 128 + f] = t0;
    part[(1 * 2 + h) * 128 + f] = t1;
    part[(2 * 2 + h) * 128 + f] = t2;
    part[(3 * 2 + h) * 128 + f] = t3;
    part[(4 * 2 + h) * 128 + f] = t4;
    part[(5 * 2 + h) * 128 + f] = r0;
    part[(6 * 2 + h) * 128 + f] = r1;
  }
  __syncthreads();

  if (tid < CH) {
    float t0 = part[(0 * 2 + 0) * 128 + tid] + part[(0 * 2 + 1) * 128 + tid];
    float t1 = part[(1 * 2 + 0) * 128 + tid] + part[(1 * 2 + 1) * 128 + tid];
    float t2 = part[(2 * 2 + 0) * 128 + tid] + part[(2 * 2 + 1) * 128 + tid];
    float t3 = part[(3 * 2 + 0) * 128 + tid] + part[(3 * 2 + 1) * 128 + tid];
    float t4 = part[(4 * 2 + 0) * 128 + tid] + part[(4 * 2 + 1) * 128 + tid];
    float t5 = part[(5 * 2 + 1) * 128 + tid];   // recent lives in half 1
    float t6 = part[(6 * 2 + 1) * 128 + tid];

    const float Lf = (float)LSEQ;
    float mean = t0 / Lf;
    float var = fmaxf(t1 - Lf * mean * mean, 0.f) / (Lf - 1.f);
    float stdE = sqrtf(var) + 1e-8f;
    float m3 = t2 / Lf - 3.f * mean * (t1 / Lf) + 2.f * mean * mean * mean;
    float skew = m3 / (stdE * stdE * stdE);
    const float nd = (float)(LSEQ - 1);
    float dmean = t3 / nd;
    float dvar = fmaxf(t4 - nd * dmean * dmean, 0.f) / (nd - 1.f);
    float dstd = sqrtf(dvar);
    const float nr = (float)NRECENT;
    float rmean = t5 / nr;
    float rvar = fmaxf(t6 - nr * rmean * rmean, 0.f) / (nr - 1.f);
    float rstd = sqrtf(rvar) + 1e-8f;

    stats[0 * CH + tid] = mean;
    stats[1 * CH + tid] = stdE;
    stats[2 * CH + tid] = skew;
    stats[3 * CH + tid] = dstd;
    stats[4 * CH + tid] = rmean;
    stats[5 * CH + tid] = rstd;
  }
  __syncthreads();

  // ---- layer 1: (768)@(768,128); half h covers k in [384h, 384h+384) ----
  {
    const int k0 = 384 * h;
    float a0 = 0, a1 = 0, a2 = 0, a3 = 0;
#pragma unroll 4
    for (int k = 0; k < 384; k += 4) {
      a0 = fmaf(stats[k0 + k + 0], W1[(size_t)(k0 + k + 0) * 128 + f], a0);
      a1 = fmaf(stats[k0 + k + 1], W1[(size_t)(k0 + k + 1) * 128 + f], a1);
      a2 = fmaf(stats[k0 + k + 2], W1[(size_t)(k0 + k + 2) * 128 + f], a2);
      a3 = fmaf(stats[k0 + k + 3], W1[(size_t)(k0 + k + 3) * 128 + f], a3);
    }
    h1p[h * 128 + f] = (a0 + a1) + (a2 + a3);
  }
  __syncthreads();
  if (tid < CH) {
    float a = h1p[tid] + h1p[128 + tid] + b1[tid];
    h1[tid] = 0.5f * a * (1.f + erff(a * 0.70710678118654752f));
  }
  __syncthreads();

  // ---- layer 2: (128)@(128,32); 8-way split-K ----
  {
    const int f2 = tid & 31, p2 = tid >> 5;  // k in [16p2, 16p2+16)
    float a0 = 0, a1 = 0;
#pragma unroll
    for (int k = 16 * p2; k < 16 * p2 + 16; k += 2) {
      a0 = fmaf(h1[k], W2[k * 32 + f2], a0);
      a1 = fmaf(h1[k + 1], W2[(k + 1) * 32 + f2], a1);
    }
    h2p[p2 * 32 + f2] = a0 + a1;
  }
  __syncthreads();
  if (tid < 32) {
    float a = b2[tid];
#pragma unroll
    for (int p2 = 0; p2 < 8; p2++) a += h2p[p2 * 32 + tid];
    h2[tid] = 0.5f * a * (1.f + erff(a * 0.70710678118654752f));
  }
  __syncthreads();

  // ---- layer 3: (32)@(32,128) + sigmoid; 2-way split-K ----
  {
    float a0 = 0, a1 = 0;
#pragma unroll
    for (int j = 16 * h; j < 16 * h + 16; j += 2) {
      a0 = fmaf(h2[j], W3[j * 128 + f], a0);
      a1 = fmaf(h2[j + 1], W3[(j + 1) * 128 + f], a1);
    }
    l3p[h * 128 + f] = a0 + a1;
  }
  __syncthreads();
  if (tid < CH) {
    float a = l3p[tid] + l3p[128 + tid] + b3[tid];
    out[(size_t)b * CH + tid] = 1.f / (1.f + expf(-a));
  }
}

extern "C" void kernel_launch(void* const* d_in, const int* in_sizes, int n_in,
                              void* d_out, int out_size, void* d_ws,
                              size_t ws_size, hipStream_t stream) {
  const float* x = (const float*)d_in[0];
  const float* W1 = (const float*)d_in[1];
  const float* b1 = (const float*)d_in[2];
  const float* W2 = (const float*)d_in[3];
  const float* b2 = (const float*)d_in[4];
  const float* W3 = (const float*)d_in[5];
  const float* b3 = (const float*)d_in[6];
  float* out = (float*)d_out;
  float* ws = (float*)d_ws;
  unsigned* cnt = (unsigned*)(ws + WS_PART_ELEMS);

  hipMemsetAsync(cnt, 0, BATCH * sizeof(unsigned), stream);
  dim3 g(NCHUNK, BATCH);
  k_fused<<<g, 256, 0, stream>>>(x, W1, b1, W2, b2, W3, b3, ws, cnt, out);
}

// Round 5
// 64.989 us; speedup vs baseline: 2.7404x; 2.7404x over previous
//
#include <hip/hip_runtime.h>
#include <math.h>

#define BATCH 64
#define LSEQ 4096
#define CH 128
#define NCHUNK 32
#define CHROWS (LSEQ / NCHUNK)   // 128
#define TROWS (CHROWS / 8)       // 16 rows per thread
#define NRECENT 1024             // chunks 24..31

typedef float f4v __attribute__((ext_vector_type(4)));

// ws layout: partials[(b*NCHUNK+chk)*5 + s][c] (5.24 MB), then BATCH u32 tickets
#define WS_PART_ELEMS ((size_t)BATCH * NCHUNK * 5 * CH)

__global__ __launch_bounds__(256) void k_fused(
    const float* __restrict__ x,
    const float* __restrict__ W1, const float* __restrict__ b1,
    const float* __restrict__ W2, const float* __restrict__ b2,
    const float* __restrict__ W3, const float* __restrict__ b3,
    float* __restrict__ ws, unsigned* __restrict__ cnt,
    float* __restrict__ out) {
  const int tid = threadIdx.x;
  const int c4 = tid & 31;        // float4 group -> channels 4*c4..4*c4+3
  const int ty = tid >> 5;        // 0..7
  const int chk = blockIdx.x;
  const int b = blockIdx.y;
  const int ts = chk * CHROWS + ty * TROWS;

  __shared__ __align__(16) float smemA[2560];
  __shared__ __align__(16) float smemB[1696];
  __shared__ unsigned ticket;

  // ================= streaming phase =================
  {
    const f4v* px =
        reinterpret_cast<const f4v*>(x + ((size_t)b * LSEQ + ts) * CH) + c4;
    const int rowstep = CH / 4;

    float sx[4] = {0, 0, 0, 0}, sx2[4] = {0, 0, 0, 0}, sx3[4] = {0, 0, 0, 0};
    float sd2[4] = {0, 0, 0, 0};
    float pv[4], first[4], sd[4];

    f4v v0 = px[0];
#pragma unroll
    for (int k = 0; k < 4; k++) {
      pv[k] = first[k] = v0[k];
      float f = pv[k], ff = f * f;
      sx[k] += f; sx2[k] += ff; sx3[k] = fmaf(ff, f, sx3[k]);
    }
#pragma unroll 5
    for (int i = 1; i < TROWS; i++) {
      f4v u = px[i * rowstep];
#pragma unroll
      for (int k = 0; k < 4; k++) {
        float f = u[k], ff = f * f;
        sx[k] += f; sx2[k] += ff; sx3[k] = fmaf(ff, f, sx3[k]);
        float d = f - pv[k];
        sd2[k] = fmaf(d, d, sd2[k]);
        pv[k] = f;
      }
    }
    if (ts + TROWS < LSEQ) {  // boundary diff into next range, telescoped sd
      f4v u = px[TROWS * rowstep];
#pragma unroll
      for (int k = 0; k < 4; k++) {
        float d = u[k] - pv[k];
        sd2[k] = fmaf(d, d, sd2[k]);
        sd[k] = u[k] - first[k];
      }
    } else {
#pragma unroll
      for (int k = 0; k < 4; k++) sd[k] = pv[k] - first[k];
    }

    float vals[20];
#pragma unroll
    for (int k = 0; k < 4; k++) {
      vals[0 + k] = sx[k];
      vals[4 + k] = sx2[k];
      vals[8 + k] = sx3[k];
      vals[12 + k] = sd[k];
      vals[16 + k] = sd2[k];
    }
#pragma unroll
    for (int j = 0; j < 20; j++) vals[j] += __shfl_xor(vals[j], 32);

    float4* red = reinterpret_cast<float4*>(smemA);  // [(s*4+w)*32+c]
    const int w = tid >> 6;
    if ((tid & 63) < 32) {
#pragma unroll
      for (int s = 0; s < 5; s++)
        red[(s * 4 + w) * 32 + c4] = make_float4(vals[s * 4 + 0], vals[s * 4 + 1],
                                                 vals[s * 4 + 2], vals[s * 4 + 3]);
    }
    __syncthreads();
    if (tid < 160) {
      const int s = tid >> 5, c = tid & 31;
      float4 r = red[(s * 4 + 0) * 32 + c];
      float4 r1 = red[(s * 4 + 1) * 32 + c];
      float4 r2 = red[(s * 4 + 2) * 32 + c];
      float4 r3 = red[(s * 4 + 3) * 32 + c];
      r.x += r1.x + r2.x + r3.x;
      r.y += r1.y + r2.y + r3.y;
      r.z += r1.z + r2.z + r3.z;
      r.w += r1.w + r2.w + r3.w;
      // agent-scope write-through stores: visible at coherence point once
      // vmcnt retires -- no L2 writeback (threadfence) needed.
      float* wsb = ws + ((size_t)(b * NCHUNK + chk) * 5 + s) * CH + 4 * c;
      __hip_atomic_store(wsb + 0, r.x, __ATOMIC_RELAXED, __HIP_MEMORY_SCOPE_AGENT);
      __hip_atomic_store(wsb + 1, r.y, __ATOMIC_RELAXED, __HIP_MEMORY_SCOPE_AGENT);
      __hip_atomic_store(wsb + 2, r.z, __ATOMIC_RELAXED, __HIP_MEMORY_SCOPE_AGENT);
      __hip_atomic_store(wsb + 3, r.w, __ATOMIC_RELAXED, __HIP_MEMORY_SCOPE_AGENT);
    }
  }
  // every wave drains its own outstanding stores, then barrier, then ticket
  asm volatile("s_waitcnt vmcnt(0)" ::: "memory");
  __syncthreads();

  if (tid == 0) ticket = atomicAdd(&cnt[b], 1u);
  __syncthreads();
  if (ticket != NCHUNK - 1) return;   // uniform per block

  // ================= finalize batch b (last block only) =================
  const int f = tid & 127;
  const int h = tid >> 7;  // 0..1

  float* part = smemA;              // [s(7)][h(2)][128]
  float* stats = smemB;             // 768
  float* h1p = smemB + 768;         // [2][128]
  float* h1 = smemB + 1024;         // 128
  float* h2p = smemB + 1152;        // [8][32]
  float* h2 = smemB + 1408;         // 32
  float* l3p = smemB + 1440;        // [2][128]

  // ---- chunk reduce: half h sums chunks [16h, 16h+16); agent-scope loads ----
  {
    float t0 = 0, t1 = 0, t2 = 0, t3 = 0, t4 = 0, r0 = 0, r1 = 0;
    const float* base = ws + (size_t)(b * NCHUNK) * 5 * CH + f;
#pragma unroll 4
    for (int c = 16 * h; c < 16 * h + 16; c++) {
      const float* p = base + (size_t)c * 5 * CH;
      float a0 = __hip_atomic_load(p + 0 * CH, __ATOMIC_RELAXED, __HIP_MEMORY_SCOPE_AGENT);
      float a1 = __hip_atomic_load(p + 1 * CH, __ATOMIC_RELAXED, __HIP_MEMORY_SCOPE_AGENT);
      float a2 = __hip_atomic_load(p + 2 * CH, __ATOMIC_RELAXED, __HIP_MEMORY_SCOPE_AGENT);
      float a3 = __hip_atomic_load(p + 3 * CH, __ATOMIC_RELAXED, __HIP_MEMORY_SCOPE_AGENT);
      float a4 = __hip_atomic_load(p + 4 * CH, __ATOMIC_RELAXED, __HIP_MEMORY_SCOPE_AGENT);
      t0 += a0; t1 += a1; t2 += a2; t3 += a3; t4 += a4;
      if (c >= 24) { r0 += a0; r1 += a1; }   // recent window, uniform branch
    }
    part[(0 * 2 + h) * 128 + f] = t0;
    part[(1 * 2 + h) * 128 + f] = t1;
    part[(2 * 2 + h) * 128 + f] = t2;
    part[(3 * 2 + h) * 128 + f] = t3;
    part[(4 * 2 + h) * 128 + f] = t4;
    part[(5 * 2 + h) * 128 + f] = r0;
    part[(6 * 2 + h) * 128 + f] = r1;
  }
  __syncthreads();

  if (tid < CH) {
    float t0 = part[(0 * 2 + 0) * 128 + tid] + part[(0 * 2 + 1) * 128 + tid];
    float t1 = part[(1 * 2 + 0) * 128 + tid] + part[(1 * 2 + 1) * 128 + tid];
    float t2 = part[(2 * 2 + 0) * 128 + tid] + part[(2 * 2 + 1) * 128 + tid];
    float t3 = part[(3 * 2 + 0) * 128 + tid] + part[(3 * 2 + 1) * 128 + tid];
    float t4 = part[(4 * 2 + 0) * 128 + tid] + part[(4 * 2 + 1) * 128 + tid];
    float t5 = part[(5 * 2 + 1) * 128 + tid];   // recent lives in half 1
    float t6 = part[(6 * 2 + 1) * 128 + tid];

    const float Lf = (float)LSEQ;
    float mean = t0 / Lf;
    float var = fmaxf(t1 - Lf * mean * mean, 0.f) / (Lf - 1.f);
    float stdE = sqrtf(var) + 1e-8f;
    float m3 = t2 / Lf - 3.f * mean * (t1 / Lf) + 2.f * mean * mean * mean;
    float skew = m3 / (stdE * stdE * stdE);
    const float nd = (float)(LSEQ - 1);
    float dmean = t3 / nd;
    float dvar = fmaxf(t4 - nd * dmean * dmean, 0.f) / (nd - 1.f);
    float dstd = sqrtf(dvar);
    const float nr = (float)NRECENT;
    float rmean = t5 / nr;
    float rvar = fmaxf(t6 - nr * rmean * rmean, 0.f) / (nr - 1.f);
    float rstd = sqrtf(rvar) + 1e-8f;

    stats[0 * CH + tid] = mean;
    stats[1 * CH + tid] = stdE;
    stats[2 * CH + tid] = skew;
    stats[3 * CH + tid] = dstd;
    stats[4 * CH + tid] = rmean;
    stats[5 * CH + tid] = rstd;
  }
  __syncthreads();

  // ---- layer 1: (768)@(768,128); half h covers k in [384h, 384h+384) ----
  {
    const int k0 = 384 * h;
    float a0 = 0, a1 = 0, a2 = 0, a3 = 0;
#pragma unroll 4
    for (int k = 0; k < 384; k += 4) {
      a0 = fmaf(stats[k0 + k + 0], W1[(size_t)(k0 + k + 0) * 128 + f], a0);
      a1 = fmaf(stats[k0 + k + 1], W1[(size_t)(k0 + k + 1) * 128 + f], a1);
      a2 = fmaf(stats[k0 + k + 2], W1[(size_t)(k0 + k + 2) * 128 + f], a2);
      a3 = fmaf(stats[k0 + k + 3], W1[(size_t)(k0 + k + 3) * 128 + f], a3);
    }
    h1p[h * 128 + f] = (a0 + a1) + (a2 + a3);
  }
  __syncthreads();
  if (tid < CH) {
    float a = h1p[tid] + h1p[128 + tid] + b1[tid];
    h1[tid] = 0.5f * a * (1.f + erff(a * 0.70710678118654752f));
  }
  __syncthreads();

  // ---- layer 2: (128)@(128,32); 8-way split-K ----
  {
    const int f2 = tid & 31, p2 = tid >> 5;  // k in [16p2, 16p2+16)
    float a0 = 0, a1 = 0;
#pragma unroll
    for (int k = 16 * p2; k < 16 * p2 + 16; k += 2) {
      a0 = fmaf(h1[k], W2[k * 32 + f2], a0);
      a1 = fmaf(h1[k + 1], W2[(k + 1) * 32 + f2], a1);
    }
    h2p[p2 * 32 + f2] = a0 + a1;
  }
  __syncthreads();
  if (tid < 32) {
    float a = b2[tid];
#pragma unroll
    for (int p2 = 0; p2 < 8; p2++) a += h2p[p2 * 32 + tid];
    h2[tid] = 0.5f * a * (1.f + erff(a * 0.70710678118654752f));
  }
  __syncthreads();

  // ---- layer 3: (32)@(32,128) + sigmoid; 2-way split-K ----
  {
    float a0 = 0, a1 = 0;
#pragma unroll
    for (int j = 16 * h; j < 16 * h + 16; j += 2) {
      a0 = fmaf(h2[j], W3[j * 128 + f], a0);
      a1 = fmaf(h2[j + 1], W3[(j + 1) * 128 + f], a1);
    }
    l3p[h * 128 + f] = a0 + a1;
  }
  __syncthreads();
  if (tid < CH) {
    float a = l3p[tid] + l3p[128 + tid] + b3[tid];
    out[(size_t)b * CH + tid] = 1.f / (1.f + expf(-a));
  }
}

extern "C" void kernel_launch(void* const* d_in, const int* in_sizes, int n_in,
                              void* d_out, int out_size, void* d_ws,
                              size_t ws_size, hipStream_t stream) {
  const float* x = (const float*)d_in[0];
  const float* W1 = (const float*)d_in[1];
  const float* b1 = (const float*)d_in[2];
  const float* W2 = (const float*)d_in[3];
  const float* b2 = (const float*)d_in[4];
  const float* W3 = (const float*)d_in[5];
  const float* b3 = (const float*)d_in[6];
  float* out = (float*)d_out;
  float* ws = (float*)d_ws;
  unsigned* cnt = (unsigned*)(ws + WS_PART_ELEMS);

  hipMemsetAsync(cnt, 0, BATCH * sizeof(unsigned), stream);
  dim3 g(NCHUNK, BATCH);
  k_fused<<<g, 256, 0, stream>>>(x, W1, b1, W2, b2, W3, b3, ws, cnt, out);
}

// Round 6
// 36.389 us; speedup vs baseline: 4.8944x; 1.7860x over previous
//
#include <hip/hip_runtime.h>
#include <math.h>

#define BATCH 64
#define LSEQ 4096
#define CH 128
#define NCHUNK 32
#define CHROWS (LSEQ / NCHUNK)   // 128
#define TROWS (CHROWS / 8)       // 16
#define NRECENT 1024             // chunks 24..31 (= groups 6,7 of 4 chunks)

// ---------------- Kernel 1: per-chunk partial sums (round-3 proven) -------
// grid (NCHUNK, BATCH), block 256 = (c4: 32) x (ty: 8)
// ws layout per (b,chunk): 5 slots x 128 ch: 0:sx 1:sx2 2:sx3 3:sd 4:sd2
__global__ __launch_bounds__(256) void k_stats_partial(
    const float* __restrict__ x, float* __restrict__ ws) {
  const int tid = threadIdx.x;
  const int c4 = tid & 31;
  const int ty = tid >> 5;
  const int chk = blockIdx.x;
  const int b = blockIdx.y;
  const int ts = chk * CHROWS + ty * TROWS;

  const float4* px =
      reinterpret_cast<const float4*>(x + ((size_t)b * LSEQ + ts) * CH) + c4;
  const int rowstep = CH / 4;

  float sx[4] = {0, 0, 0, 0}, sx2[4] = {0, 0, 0, 0}, sx3[4] = {0, 0, 0, 0};
  float sd2[4] = {0, 0, 0, 0};
  float pv[4], first[4], sd[4];

  float4 v0 = px[0];
  pv[0] = first[0] = v0.x;
  pv[1] = first[1] = v0.y;
  pv[2] = first[2] = v0.z;
  pv[3] = first[3] = v0.w;
#pragma unroll
  for (int k = 0; k < 4; k++) {
    float f = pv[k], ff = f * f;
    sx[k] += f; sx2[k] += ff; sx3[k] = fmaf(ff, f, sx3[k]);
  }
#pragma unroll 5
  for (int i = 1; i < TROWS; i++) {
    float4 u = px[i * rowstep];
    float cur[4] = {u.x, u.y, u.z, u.w};
#pragma unroll
    for (int k = 0; k < 4; k++) {
      float f = cur[k], ff = f * f;
      sx[k] += f; sx2[k] += ff; sx3[k] = fmaf(ff, f, sx3[k]);
      float d = f - pv[k];
      sd2[k] = fmaf(d, d, sd2[k]);
      pv[k] = f;
    }
  }
  if (ts + TROWS < LSEQ) {
    float4 u = px[TROWS * rowstep];
    float cur[4] = {u.x, u.y, u.z, u.w};
#pragma unroll
    for (int k = 0; k < 4; k++) {
      float d = cur[k] - pv[k];
      sd2[k] = fmaf(d, d, sd2[k]);
      sd[k] = cur[k] - first[k];
    }
  } else {
#pragma unroll
    for (int k = 0; k < 4; k++) sd[k] = pv[k] - first[k];
  }

  float vals[20];
#pragma unroll
  for (int k = 0; k < 4; k++) {
    vals[0 + k] = sx[k];
    vals[4 + k] = sx2[k];
    vals[8 + k] = sx3[k];
    vals[12 + k] = sd[k];
    vals[16 + k] = sd2[k];
  }
#pragma unroll
  for (int j = 0; j < 20; j++) vals[j] += __shfl_xor(vals[j], 32);

  __shared__ float4 red[5][4][32];
  const int w = tid >> 6;
  const int lane = tid & 63;
  if (lane < 32) {
#pragma unroll
    for (int s = 0; s < 5; s++)
      red[s][w][c4] = make_float4(vals[s * 4 + 0], vals[s * 4 + 1],
                                  vals[s * 4 + 2], vals[s * 4 + 3]);
  }
  __syncthreads();
  if (tid < 160) {
    const int s = tid >> 5, c = tid & 31;
    float4 r = red[s][0][c];
    float4 r1 = red[s][1][c], r2 = red[s][2][c], r3 = red[s][3][c];
    r.x += r1.x + r2.x + r3.x;
    r.y += r1.y + r2.y + r3.y;
    r.z += r1.z + r2.z + r3.z;
    r.w += r1.w + r2.w + r3.w;
    float* wsb = ws + ((size_t)(b * NCHUNK + chk) * 5 + s) * CH;
    reinterpret_cast<float4*>(wsb)[c] = r;
  }
}

// ---------------- Kernel 2: finalize stats + MLP (1024 thr, deep split-K) --
// grid (BATCH), block 1024: f = tid&127, g = tid>>7 (0..7)
__global__ __launch_bounds__(1024) void k_stats_mlp(
    const float* __restrict__ ws,
    const float* __restrict__ W1, const float* __restrict__ b1,
    const float* __restrict__ W2, const float* __restrict__ b2,
    const float* __restrict__ W3, const float* __restrict__ b3,
    float* __restrict__ out) {
  const int b = blockIdx.x;
  const int tid = threadIdx.x;
  const int f = tid & 127;
  const int g = tid >> 7;  // 0..7

  __shared__ float part[5][8][CH];   // 20 KB
  __shared__ float stats[6 * CH];
  __shared__ float h1p[8][128];
  __shared__ float h1[128];
  __shared__ float h2p[32][32];
  __shared__ float h2[32];
  __shared__ float l3p[8][128];

  // ---- chunk reduce: group g sums chunks [4g, 4g+4) for channel f ----
  {
    float t0 = 0, t1 = 0, t2 = 0, t3 = 0, t4 = 0;
#pragma unroll
    for (int chk = g * 4; chk < g * 4 + 4; chk++) {
      const float* p = ws + ((size_t)(b * NCHUNK + chk) * 5) * CH + f;
      t0 += p[0 * CH];
      t1 += p[1 * CH];
      t2 += p[2 * CH];
      t3 += p[3 * CH];
      t4 += p[4 * CH];
    }
    part[0][g][f] = t0;
    part[1][g][f] = t1;
    part[2][g][f] = t2;
    part[3][g][f] = t3;
    part[4][g][f] = t4;
  }
  __syncthreads();

  if (tid < CH) {
    float t0 = 0, t1 = 0, t2 = 0, t3 = 0, t4 = 0, t5 = 0, t6 = 0;
#pragma unroll
    for (int k = 0; k < 8; k++) {
      float a0 = part[0][k][tid], a1 = part[1][k][tid];
      t0 += a0; t1 += a1;
      t2 += part[2][k][tid];
      t3 += part[3][k][tid];
      t4 += part[4][k][tid];
      if (k >= 6) { t5 += a0; t6 += a1; }  // recent = chunks 24..31
    }

    const float Lf = (float)LSEQ;
    float mean = t0 / Lf;
    float var = fmaxf(t1 - Lf * mean * mean, 0.f) / (Lf - 1.f);
    float stdE = sqrtf(var) + 1e-8f;
    float m3 = t2 / Lf - 3.f * mean * (t1 / Lf) + 2.f * mean * mean * mean;
    float skew = m3 / (stdE * stdE * stdE);
    const float nd = (float)(LSEQ - 1);
    float dmean = t3 / nd;
    float dvar = fmaxf(t4 - nd * dmean * dmean, 0.f) / (nd - 1.f);
    float dstd = sqrtf(dvar);
    const float nr = (float)NRECENT;
    float rmean = t5 / nr;
    float rvar = fmaxf(t6 - nr * rmean * rmean, 0.f) / (nr - 1.f);
    float rstd = sqrtf(rvar) + 1e-8f;

    stats[0 * CH + tid] = mean;
    stats[1 * CH + tid] = stdE;
    stats[2 * CH + tid] = skew;
    stats[3 * CH + tid] = dstd;
    stats[4 * CH + tid] = rmean;
    stats[5 * CH + tid] = rstd;
  }
  __syncthreads();

  // ---- layer 1: (768)@(768,128); group g covers k in [96g, 96g+96) ----
  {
    const int k0 = 96 * g;
    float a0 = 0, a1 = 0, a2 = 0, a3 = 0;
#pragma unroll 6
    for (int k = 0; k < 96; k += 4) {
      a0 = fmaf(stats[k0 + k + 0], W1[(size_t)(k0 + k + 0) * 128 + f], a0);
      a1 = fmaf(stats[k0 + k + 1], W1[(size_t)(k0 + k + 1) * 128 + f], a1);
      a2 = fmaf(stats[k0 + k + 2], W1[(size_t)(k0 + k + 2) * 128 + f], a2);
      a3 = fmaf(stats[k0 + k + 3], W1[(size_t)(k0 + k + 3) * 128 + f], a3);
    }
    h1p[g][f] = (a0 + a1) + (a2 + a3);
  }
  __syncthreads();
  if (tid < CH) {
    float a = b1[tid];
#pragma unroll
    for (int k = 0; k < 8; k++) a += h1p[k][tid];
    h1[tid] = 0.5f * a * (1.f + erff(a * 0.70710678118654752f));
  }
  __syncthreads();

  // ---- layer 2: (128)@(128,32); 32-way split-K ----
  {
    const int f2 = tid & 31, p2 = tid >> 5;  // p2: 0..31, k in [4p2, 4p2+4)
    float a0 = 0, a1 = 0;
#pragma unroll
    for (int k = 4 * p2; k < 4 * p2 + 4; k += 2) {
      a0 = fmaf(h1[k], W2[k * 32 + f2], a0);
      a1 = fmaf(h1[k + 1], W2[(k + 1) * 32 + f2], a1);
    }
    h2p[p2][f2] = a0 + a1;
  }
  __syncthreads();
  if (tid < 32) {
    float a = b2[tid];
#pragma unroll
    for (int p2 = 0; p2 < 32; p2++) a += h2p[p2][tid];
    h2[tid] = 0.5f * a * (1.f + erff(a * 0.70710678118654752f));
  }
  __syncthreads();

  // ---- layer 3: (32)@(32,128) + sigmoid; 8-way split-K ----
  {
    float a0 = 0, a1 = 0;
#pragma unroll
    for (int j = 4 * g; j < 4 * g + 4; j += 2) {
      a0 = fmaf(h2[j], W3[j * 128 + f], a0);
      a1 = fmaf(h2[j + 1], W3[(j + 1) * 128 + f], a1);
    }
    l3p[g][f] = a0 + a1;
  }
  __syncthreads();
  if (tid < CH) {
    float a = b3[tid];
#pragma unroll
    for (int k = 0; k < 8; k++) a += l3p[k][tid];
    out[(size_t)b * CH + tid] = 1.f / (1.f + expf(-a));
  }
}

extern "C" void kernel_launch(void* const* d_in, const int* in_sizes, int n_in,
                              void* d_out, int out_size, void* d_ws,
                              size_t ws_size, hipStream_t stream) {
  const float* x = (const float*)d_in[0];
  const float* W1 = (const float*)d_in[1];
  const float* b1 = (const float*)d_in[2];
  const float* W2 = (const float*)d_in[3];
  const float* b2 = (const float*)d_in[4];
  const float* W3 = (const float*)d_in[5];
  const float* b3 = (const float*)d_in[6];
  float* out = (float*)d_out;
  float* ws = (float*)d_ws;

  dim3 g1(NCHUNK, BATCH);
  k_stats_partial<<<g1, 256, 0, stream>>>(x, ws);
  k_stats_mlp<<<BATCH, 1024, 0, stream>>>(ws, W1, b1, W2, b2, W3, b3, out);
}